// Round 5
// baseline (755.271 us; speedup 1.0000x reference)
//
#include <hip/hip_runtime.h>

#define NN 256
#define MM 65536
#define TBL 131072
#define TBL_MASK (TBL - 1)

// ---------------- initial coloring ----------------

__global__ void build_adj(const int* __restrict__ ei, int* __restrict__ A, int E) {
    int e = blockIdx.x * blockDim.x + threadIdx.x;
    if (e < E) {
        int s = ei[e];
        int d = ei[E + e];
        A[s * NN + d] = 1;
    }
}

__device__ __forceinline__ unsigned key0_of(const int* x, const int* A, int i, int j, int m) {
    return ((unsigned)x[i] << 5) | ((unsigned)x[j] << 1) | (unsigned)A[m];
}

__global__ void init_key_pass(const int* __restrict__ x, const int* __restrict__ A,
                              unsigned* __restrict__ minpos0, unsigned* __restrict__ cnt0) {
    int m = blockIdx.x * blockDim.x + threadIdx.x;
    int i = m >> 8, j = m & 255;
    unsigned key = key0_of(x, A, i, j, m);
    // torch order: all permutations (i != j) lexicographically, then the diagonal
    unsigned pos = (i == j) ? (unsigned)(NN * (NN - 1) + i)
                            : (unsigned)(i * (NN - 1) + (j < i ? j : j - 1));
    atomicMin(&minpos0[key], pos);
    atomicAdd(&cnt0[key], 1u);
}

__global__ void mark_first_small(const unsigned* __restrict__ cnt0,
                                 const unsigned* __restrict__ minpos0,
                                 unsigned* __restrict__ flags) {
    int k = blockIdx.x * blockDim.x + threadIdx.x;
    if (k < 512 && cnt0[k]) flags[minpos0[k]] = 1u;
}

// exclusive prefix sum over 65536 unsigned, one block of 1024 threads, 64 elems each
__global__ void scan64k(const unsigned* __restrict__ in, unsigned* __restrict__ out) {
    __shared__ unsigned part[1024];
    int t = threadIdx.x;
    int base = t * 64;
    unsigned sum = 0;
#pragma unroll
    for (int k = 0; k < 64; k++) sum += in[base + k];
    part[t] = sum;
    __syncthreads();
    for (int off = 1; off < 1024; off <<= 1) {
        unsigned v = (t >= off) ? part[t - off] : 0u;
        __syncthreads();
        part[t] += v;
        __syncthreads();
    }
    unsigned run = part[t] - sum;  // exclusive base for this chunk
    for (int k = 0; k < 64; k++) {
        unsigned v = in[base + k];
        out[base + k] = run;
        run += v;
    }
}

__global__ void rank_hist_small(const unsigned* __restrict__ cnt0,
                                const unsigned* __restrict__ minpos0,
                                const unsigned* __restrict__ rankat,
                                unsigned* __restrict__ rank0, int* __restrict__ hist) {
    int k = blockIdx.x * blockDim.x + threadIdx.x;
    if (k < 512 && cnt0[k]) {
        unsigned rk = rankat[minpos0[k]];
        rank0[k] = rk;
        hist[rk] = (int)cnt0[k];
    }
}

__global__ void write_labels0(const int* __restrict__ x, const int* __restrict__ A,
                              const unsigned* __restrict__ rank0, int* __restrict__ labels) {
    int m = blockIdx.x * blockDim.x + threadIdx.x;
    int i = m >> 8, j = m & 255;
    labels[m] = (int)rank0[key0_of(x, A, i, j, m)];
}

// ---------------- per-layer: row/col canonicalization ----------------

__device__ __forceinline__ void bitonic256(int* s, int t) {
    for (int k = 2; k <= NN; k <<= 1) {
        for (int jj = k >> 1; jj > 0; jj >>= 1) {
            int ixj = t ^ jj;
            if (ixj > t) {
                int a = s[t], b = s[ixj];
                bool asc = ((t & k) == 0);
                if (asc ? (a > b) : (a < b)) {
                    s[t] = b;
                    s[ixj] = a;
                }
            }
            __syncthreads();
        }
    }
}

__global__ void sort_rows(const int* __restrict__ labels, int* __restrict__ out) {
    __shared__ int s[NN];
    int i = blockIdx.x, t = threadIdx.x;
    s[t] = labels[i * NN + t];
    __syncthreads();
    bitonic256(s, t);
    out[i * NN + t] = s[t];
}

__global__ void sort_cols(const int* __restrict__ labels, int* __restrict__ out) {
    __shared__ int s[NN];
    int j = blockIdx.x, t = threadIdx.x;
    s[t] = labels[t * NN + j];
    __syncthreads();
    bitonic256(s, t);
    out[j * NN + t] = s[t];
}

// rep[i] = min index j such that sorted row j == sorted row i (exact comparison)
__global__ void row_rep(const int* __restrict__ sorted, int* __restrict__ rep) {
    int i = blockIdx.x, t = threadIdx.x;
    __shared__ int mine[NN];
    mine[t] = sorted[i * NN + t];
    __syncthreads();
    int result = i;
    for (int j = 0; j < i; j++) {
        int eq = (sorted[j * NN + t] == mine[t]);
        if (__syncthreads_and(eq)) {
            result = j;
            break;
        }
    }
    if (t == 0) rep[i] = result;
}

// ---------------- per-layer: exact relabel via hash table ----------------

__global__ void relabel_insert(const int* __restrict__ labels, const int* __restrict__ r,
                               const int* __restrict__ c, unsigned long long* __restrict__ tk,
                               unsigned* __restrict__ minpos, unsigned* __restrict__ cnt,
                               unsigned* __restrict__ slotidx) {
    int m = blockIdx.x * blockDim.x + threadIdx.x;
    int i = m >> 8, j = m & 255;
    unsigned key = (unsigned)labels[m] | ((unsigned)r[i] << 16) | ((unsigned)c[j] << 24);
    unsigned long long kk = (unsigned long long)key + 1ull;  // 0 = empty
    unsigned h = ((key * 2654435761u) >> 15) & TBL_MASK;
    for (;;) {
        unsigned long long prev = atomicCAS(&tk[h], 0ull, kk);
        if (prev == 0ull || prev == kk) break;
        h = (h + 1) & TBL_MASK;
    }
    slotidx[m] = h;
    atomicMin(&minpos[h], (unsigned)m);
    atomicAdd(&cnt[h], 1u);
}

__global__ void mark_slots(const unsigned long long* __restrict__ tk,
                           const unsigned* __restrict__ minpos, unsigned* __restrict__ flags) {
    int s = blockIdx.x * blockDim.x + threadIdx.x;
    if (tk[s]) flags[minpos[s]] = 1u;
}

__global__ void slot_rank_hist(const unsigned long long* __restrict__ tk,
                               const unsigned* __restrict__ minpos,
                               const unsigned* __restrict__ cnt,
                               const unsigned* __restrict__ rankat,
                               unsigned* __restrict__ rankslot, int* __restrict__ hist) {
    int s = blockIdx.x * blockDim.x + threadIdx.x;
    if (tk[s]) {
        unsigned rk = rankat[minpos[s]];
        rankslot[s] = rk;
        hist[rk] = (int)cnt[s];
    }
}

__global__ void apply_ranks(const unsigned* __restrict__ slotidx,
                            const unsigned* __restrict__ rankslot, int* __restrict__ labels2) {
    int m = blockIdx.x * blockDim.x + threadIdx.x;
    labels2[m] = (int)rankslot[slotidx[m]];
}

extern "C" void kernel_launch(void* const* d_in, const int* in_sizes, int n_in,
                              void* d_out, int out_size, void* d_ws, size_t ws_size,
                              hipStream_t stream) {
    const int* x = (const int*)d_in[0];
    const int* ei = (const int*)d_in[1];
    const int E = in_sizes[1] / 2;
    int* out = (int*)d_out;  // reference outputs are int32 histograms

    // ---- workspace carve-up (aligned to 512B) ----
    char* w = (char*)d_ws;
    size_t off = 0;
    auto alloc = [&](size_t bytes) -> void* {
        void* p = w + off;
        off = (off + bytes + 511) & ~(size_t)511;
        return p;
    };
    unsigned long long* tk = (unsigned long long*)alloc(TBL * 8);
    unsigned* minpos = (unsigned*)alloc(TBL * 4);
    unsigned* cnt = (unsigned*)alloc(TBL * 4);
    unsigned* rankslot = (unsigned*)alloc(TBL * 4);
    unsigned* slotidx = (unsigned*)alloc(MM * 4);
    unsigned* flags = (unsigned*)alloc(MM * 4);
    unsigned* rankat = (unsigned*)alloc(MM * 4);
    int* A = (int*)alloc(MM * 4);
    int* labels = (int*)alloc(MM * 4);
    int* labels2 = (int*)alloc(MM * 4);
    int* rowsorted = (int*)alloc(MM * 4);
    int* colsorted = (int*)alloc(MM * 4);
    int* rvec = (int*)alloc(NN * 4);
    int* cvec = (int*)alloc(NN * 4);
    unsigned* minpos0 = (unsigned*)alloc(512 * 4);
    unsigned* cnt0 = (unsigned*)alloc(512 * 4);
    unsigned* rank0 = (unsigned*)alloc(512 * 4);

    // ---- output: zero all three histograms ----
    (void)hipMemsetAsync(d_out, 0, (size_t)out_size * sizeof(int), stream);

    // ---- adjacency ----
    (void)hipMemsetAsync(A, 0, MM * 4, stream);
    build_adj<<<(E + 255) / 256, 256, 0, stream>>>(ei, A, E);

    // ---- initial coloring (9-bit signature, direct table) ----
    (void)hipMemsetAsync(minpos0, 0xFF, 512 * 4, stream);
    (void)hipMemsetAsync(cnt0, 0, 512 * 4, stream);
    init_key_pass<<<MM / 256, 256, 0, stream>>>(x, A, minpos0, cnt0);
    (void)hipMemsetAsync(flags, 0, MM * 4, stream);
    mark_first_small<<<2, 256, 0, stream>>>(cnt0, minpos0, flags);
    scan64k<<<1, 1024, 0, stream>>>(flags, rankat);
    rank_hist_small<<<2, 256, 0, stream>>>(cnt0, minpos0, rankat, rank0, out);
    write_labels0<<<MM / 256, 256, 0, stream>>>(x, A, rank0, labels);

    // ---- refinement layers ----
    int* lab = labels;
    int* lab2 = labels2;
    for (int layer = 0; layer < 2; ++layer) {
        sort_rows<<<NN, NN, 0, stream>>>(lab, rowsorted);
        sort_cols<<<NN, NN, 0, stream>>>(lab, colsorted);
        row_rep<<<NN, NN, 0, stream>>>(rowsorted, rvec);
        row_rep<<<NN, NN, 0, stream>>>(colsorted, cvec);

        (void)hipMemsetAsync(tk, 0, TBL * 8, stream);
        (void)hipMemsetAsync(minpos, 0xFF, TBL * 4, stream);
        (void)hipMemsetAsync(cnt, 0, TBL * 4, stream);
        relabel_insert<<<MM / 256, 256, 0, stream>>>(lab, rvec, cvec, tk, minpos, cnt, slotidx);

        (void)hipMemsetAsync(flags, 0, MM * 4, stream);
        mark_slots<<<TBL / 256, 256, 0, stream>>>(tk, minpos, flags);
        scan64k<<<1, 1024, 0, stream>>>(flags, rankat);
        slot_rank_hist<<<TBL / 256, 256, 0, stream>>>(tk, minpos, cnt, rankat, rankslot,
                                                      out + (size_t)(layer + 1) * MM);
        apply_ranks<<<MM / 256, 256, 0, stream>>>(slotidx, rankslot, lab2);

        int* tmp = lab;
        lab = lab2;
        lab2 = tmp;
    }
}

// Round 6
// 286.113 us; speedup vs baseline: 2.6398x; 2.6398x over previous
//
#include <hip/hip_runtime.h>

#define NN 256
#define MM 65536
#define TBL 131072
#define TBL_MASK (TBL - 1)

// ---------------- initial coloring ----------------

__global__ void build_adj(const int* __restrict__ ei, int* __restrict__ A, int E) {
    int e = blockIdx.x * blockDim.x + threadIdx.x;
    if (e < E) {
        int s = ei[e];
        int d = ei[E + e];
        A[s * NN + d] = 1;
    }
}

__device__ __forceinline__ unsigned key0_of(const int* x, const int* A, int i, int j, int m) {
    return ((unsigned)x[i] << 5) | ((unsigned)x[j] << 1) | (unsigned)A[m];
}

__global__ void init_key_pass(const int* __restrict__ x, const int* __restrict__ A,
                              unsigned* __restrict__ minpos0, unsigned* __restrict__ cnt0) {
    int m = blockIdx.x * blockDim.x + threadIdx.x;
    int i = m >> 8, j = m & 255;
    unsigned key = key0_of(x, A, i, j, m);
    // torch order: all permutations (i != j) lexicographically, then the diagonal
    unsigned pos = (i == j) ? (unsigned)(NN * (NN - 1) + i)
                            : (unsigned)(i * (NN - 1) + (j < i ? j : j - 1));
    atomicMin(&minpos0[key], pos);
    atomicAdd(&cnt0[key], 1u);
}

__global__ void mark_first_small(const unsigned* __restrict__ cnt0,
                                 const unsigned* __restrict__ minpos0,
                                 unsigned* __restrict__ flags) {
    int k = blockIdx.x * blockDim.x + threadIdx.x;
    if (k < 512 && cnt0[k]) flags[minpos0[k]] = 1u;
}

// exclusive prefix sum over 65536 unsigned, one block of 1024 threads, 64 elems each
__global__ void scan64k(const unsigned* __restrict__ in, unsigned* __restrict__ out) {
    __shared__ unsigned part[1024];
    int t = threadIdx.x;
    int base = t * 64;
    unsigned sum = 0;
#pragma unroll
    for (int k = 0; k < 64; k++) sum += in[base + k];
    part[t] = sum;
    __syncthreads();
    for (int off = 1; off < 1024; off <<= 1) {
        unsigned v = (t >= off) ? part[t - off] : 0u;
        __syncthreads();
        part[t] += v;
        __syncthreads();
    }
    unsigned run = part[t] - sum;  // exclusive base for this chunk
    for (int k = 0; k < 64; k++) {
        unsigned v = in[base + k];
        out[base + k] = run;
        run += v;
    }
}

__global__ void rank_hist_small(const unsigned* __restrict__ cnt0,
                                const unsigned* __restrict__ minpos0,
                                const unsigned* __restrict__ rankat,
                                unsigned* __restrict__ rank0, int* __restrict__ hist) {
    int k = blockIdx.x * blockDim.x + threadIdx.x;
    if (k < 512 && cnt0[k]) {
        unsigned rk = rankat[minpos0[k]];
        rank0[k] = rk;
        hist[rk] = (int)cnt0[k];
    }
}

__global__ void write_labels0(const int* __restrict__ x, const int* __restrict__ A,
                              const unsigned* __restrict__ rank0, int* __restrict__ labels) {
    int m = blockIdx.x * blockDim.x + threadIdx.x;
    int i = m >> 8, j = m & 255;
    labels[m] = (int)rank0[key0_of(x, A, i, j, m)];
}

// ---------------- per-layer: row/col canonicalization ----------------

__device__ __forceinline__ void bitonic256(int* s, int t) {
    for (int k = 2; k <= NN; k <<= 1) {
        for (int jj = k >> 1; jj > 0; jj >>= 1) {
            int ixj = t ^ jj;
            if (ixj > t) {
                int a = s[t], b = s[ixj];
                bool asc = ((t & k) == 0);
                if (asc ? (a > b) : (a < b)) {
                    s[t] = b;
                    s[ixj] = a;
                }
            }
            __syncthreads();
        }
    }
}

// also initializes rep[i] = i (consumed by row_rep_pairs via atomicMin)
__global__ void sort_rows(const int* __restrict__ labels, int* __restrict__ out,
                          int* __restrict__ rep) {
    __shared__ int s[NN];
    int i = blockIdx.x, t = threadIdx.x;
    if (t == 0) rep[i] = i;
    s[t] = labels[i * NN + t];
    __syncthreads();
    bitonic256(s, t);
    out[i * NN + t] = s[t];
}

__global__ void sort_cols(const int* __restrict__ labels, int* __restrict__ out,
                          int* __restrict__ rep) {
    __shared__ int s[NN];
    int j = blockIdx.x, t = threadIdx.x;
    if (t == 0) rep[j] = j;
    s[t] = labels[t * NN + j];
    __syncthreads();
    bitonic256(s, t);
    out[j * NN + t] = s[t];
}

// rep[i] = min j such that sorted row j == sorted row i.
// One 64-lane wave per (i, j) pair, 4 waves per block. Rows are L2-resident.
__global__ void row_rep_pairs(const int* __restrict__ sorted, int* __restrict__ rep) {
    int i = blockIdx.x;
    int wid = threadIdx.x >> 6;            // wave id within block: 0..3
    int lane = threadIdx.x & 63;
    int j = (blockIdx.y << 2) + wid;       // 0..255
    if (j >= i) return;
    const int* ri = sorted + i * NN;
    const int* rj = sorted + j * NN;
    bool eq = true;
#pragma unroll
    for (int k = 0; k < NN; k += 64) {
        eq = eq && (ri[lane + k] == rj[lane + k]);
    }
    if (__all(eq)) {
        if (lane == 0) atomicMin(&rep[i], j);
    }
}

// ---------------- per-layer: exact relabel via hash table ----------------

__global__ void relabel_insert(const int* __restrict__ labels, const int* __restrict__ r,
                               const int* __restrict__ c, unsigned long long* __restrict__ tk,
                               unsigned* __restrict__ minpos, unsigned* __restrict__ cnt,
                               unsigned* __restrict__ slotidx) {
    int m = blockIdx.x * blockDim.x + threadIdx.x;
    int i = m >> 8, j = m & 255;
    unsigned key = (unsigned)labels[m] | ((unsigned)r[i] << 16) | ((unsigned)c[j] << 24);
    unsigned long long kk = (unsigned long long)key + 1ull;  // 0 = empty
    unsigned h = ((key * 2654435761u) >> 15) & TBL_MASK;
    for (;;) {
        unsigned long long prev = atomicCAS(&tk[h], 0ull, kk);
        if (prev == 0ull || prev == kk) break;
        h = (h + 1) & TBL_MASK;
    }
    slotidx[m] = h;
    atomicMin(&minpos[h], (unsigned)m);
    atomicAdd(&cnt[h], 1u);
}

__global__ void mark_slots(const unsigned long long* __restrict__ tk,
                           const unsigned* __restrict__ minpos, unsigned* __restrict__ flags) {
    int s = blockIdx.x * blockDim.x + threadIdx.x;
    if (tk[s]) flags[minpos[s]] = 1u;
}

__global__ void slot_rank_hist(const unsigned long long* __restrict__ tk,
                               const unsigned* __restrict__ minpos,
                               const unsigned* __restrict__ cnt,
                               const unsigned* __restrict__ rankat,
                               unsigned* __restrict__ rankslot, int* __restrict__ hist) {
    int s = blockIdx.x * blockDim.x + threadIdx.x;
    if (tk[s]) {
        unsigned rk = rankat[minpos[s]];
        rankslot[s] = rk;
        hist[rk] = (int)cnt[s];
    }
}

__global__ void apply_ranks(const unsigned* __restrict__ slotidx,
                            const unsigned* __restrict__ rankslot, int* __restrict__ labels2) {
    int m = blockIdx.x * blockDim.x + threadIdx.x;
    labels2[m] = (int)rankslot[slotidx[m]];
}

extern "C" void kernel_launch(void* const* d_in, const int* in_sizes, int n_in,
                              void* d_out, int out_size, void* d_ws, size_t ws_size,
                              hipStream_t stream) {
    const int* x = (const int*)d_in[0];
    const int* ei = (const int*)d_in[1];
    const int E = in_sizes[1] / 2;
    int* out = (int*)d_out;  // reference outputs are int32 histograms

    // ---- workspace carve-up (aligned to 512B) ----
    char* w = (char*)d_ws;
    size_t off = 0;
    auto alloc = [&](size_t bytes) -> void* {
        void* p = w + off;
        off = (off + bytes + 511) & ~(size_t)511;
        return p;
    };
    unsigned long long* tk = (unsigned long long*)alloc(TBL * 8);
    unsigned* minpos = (unsigned*)alloc(TBL * 4);
    unsigned* cnt = (unsigned*)alloc(TBL * 4);
    unsigned* rankslot = (unsigned*)alloc(TBL * 4);
    unsigned* slotidx = (unsigned*)alloc(MM * 4);
    unsigned* flags = (unsigned*)alloc(MM * 4);
    unsigned* rankat = (unsigned*)alloc(MM * 4);
    int* A = (int*)alloc(MM * 4);
    int* labels = (int*)alloc(MM * 4);
    int* labels2 = (int*)alloc(MM * 4);
    int* rowsorted = (int*)alloc(MM * 4);
    int* colsorted = (int*)alloc(MM * 4);
    int* rvec = (int*)alloc(NN * 4);
    int* cvec = (int*)alloc(NN * 4);
    unsigned* minpos0 = (unsigned*)alloc(512 * 4);
    unsigned* cnt0 = (unsigned*)alloc(512 * 4);
    unsigned* rank0 = (unsigned*)alloc(512 * 4);

    // ---- output: zero all three histograms ----
    (void)hipMemsetAsync(d_out, 0, (size_t)out_size * sizeof(int), stream);

    // ---- adjacency ----
    (void)hipMemsetAsync(A, 0, MM * 4, stream);
    build_adj<<<(E + 255) / 256, 256, 0, stream>>>(ei, A, E);

    // ---- initial coloring (9-bit signature, direct table) ----
    (void)hipMemsetAsync(minpos0, 0xFF, 512 * 4, stream);
    (void)hipMemsetAsync(cnt0, 0, 512 * 4, stream);
    init_key_pass<<<MM / 256, 256, 0, stream>>>(x, A, minpos0, cnt0);
    (void)hipMemsetAsync(flags, 0, MM * 4, stream);
    mark_first_small<<<2, 256, 0, stream>>>(cnt0, minpos0, flags);
    scan64k<<<1, 1024, 0, stream>>>(flags, rankat);
    rank_hist_small<<<2, 256, 0, stream>>>(cnt0, minpos0, rankat, rank0, out);
    write_labels0<<<MM / 256, 256, 0, stream>>>(x, A, rank0, labels);

    // ---- refinement layers ----
    int* lab = labels;
    int* lab2 = labels2;
    for (int layer = 0; layer < 2; ++layer) {
        sort_rows<<<NN, NN, 0, stream>>>(lab, rowsorted, rvec);
        sort_cols<<<NN, NN, 0, stream>>>(lab, colsorted, cvec);
        row_rep_pairs<<<dim3(NN, NN / 4), 256, 0, stream>>>(rowsorted, rvec);
        row_rep_pairs<<<dim3(NN, NN / 4), 256, 0, stream>>>(colsorted, cvec);

        (void)hipMemsetAsync(tk, 0, TBL * 8, stream);
        (void)hipMemsetAsync(minpos, 0xFF, TBL * 4, stream);
        (void)hipMemsetAsync(cnt, 0, TBL * 4, stream);
        relabel_insert<<<MM / 256, 256, 0, stream>>>(lab, rvec, cvec, tk, minpos, cnt, slotidx);

        (void)hipMemsetAsync(flags, 0, MM * 4, stream);
        mark_slots<<<TBL / 256, 256, 0, stream>>>(tk, minpos, flags);
        scan64k<<<1, 1024, 0, stream>>>(flags, rankat);
        slot_rank_hist<<<TBL / 256, 256, 0, stream>>>(tk, minpos, cnt, rankat, rankslot,
                                                      out + (size_t)(layer + 1) * MM);
        apply_ranks<<<MM / 256, 256, 0, stream>>>(slotidx, rankslot, lab2);

        int* tmp = lab;
        lab = lab2;
        lab2 = tmp;
    }
}

// Round 10
// 206.334 us; speedup vs baseline: 3.6604x; 1.3866x over previous
//
#include <hip/hip_runtime.h>

#define NN 256
#define MM 65536
#define TBL 131072
#define TBL_MASK (TBL - 1)

// ---------------- initial coloring ----------------

__global__ void build_adj(const int* __restrict__ ei, int* __restrict__ A, int E) {
    int e = blockIdx.x * blockDim.x + threadIdx.x;
    if (e < E) {
        int s = ei[e];
        int d = ei[E + e];
        A[s * NN + d] = 1;
    }
}

__device__ __forceinline__ unsigned key0_of(const int* x, const int* A, int i, int j, int m) {
    return ((unsigned)x[i] << 5) | ((unsigned)x[j] << 1) | (unsigned)A[m];
}

// minpos encoded as atomicMax(~pos) so the table zero-inits (0 == empty).
__global__ void init_key_pass(const int* __restrict__ x, const int* __restrict__ A,
                              unsigned* __restrict__ mp0, unsigned* __restrict__ c0) {
    int m = blockIdx.x * blockDim.x + threadIdx.x;
    int i = m >> 8, j = m & 255;
    unsigned key = key0_of(x, A, i, j, m);
    // torch order: all permutations (i != j) lexicographically, then the diagonal
    unsigned pos = (i == j) ? (unsigned)(NN * (NN - 1) + i)
                            : (unsigned)(i * (NN - 1) + (j < i ? j : j - 1));
    atomicMax(&mp0[key], ~pos);
    atomicAdd(&c0[key], 1u);
}

// one block, 512 threads: rank groups by first-occurrence via O(512^2) counting
__global__ void rank0_fused(const unsigned* __restrict__ mp0, const unsigned* __restrict__ c0,
                            unsigned* __restrict__ rank0, int* __restrict__ hist) {
    __shared__ unsigned pos_s[512];
    int k = threadIdx.x;
    unsigned c = c0[k];
    pos_s[k] = c ? ~mp0[k] : 0xFFFFFFFFu;
    __syncthreads();
    if (c) {
        unsigned my = pos_s[k];
        int rk = 0;
        for (int kk = 0; kk < 512; ++kk) rk += (pos_s[kk] < my);
        rank0[k] = (unsigned)rk;
        hist[rk] = (int)c;
    }
}

__global__ void write_labels0(const int* __restrict__ x, const int* __restrict__ A,
                              const unsigned* __restrict__ rank0, int* __restrict__ labels) {
    int m = blockIdx.x * blockDim.x + threadIdx.x;
    int i = m >> 8, j = m & 255;
    labels[m] = (int)rank0[key0_of(x, A, i, j, m)];
}

// ---------------- per-layer: row/col canonicalization ----------------

__device__ __forceinline__ void bitonic256(int* s, int t) {
    for (int k = 2; k <= NN; k <<= 1) {
        for (int jj = k >> 1; jj > 0; jj >>= 1) {
            int ixj = t ^ jj;
            if (ixj > t) {
                int a = s[t], b = s[ixj];
                bool asc = ((t & k) == 0);
                if (asc ? (a > b) : (a < b)) {
                    s[t] = b;
                    s[ixj] = a;
                }
            }
            __syncthreads();
        }
    }
}

// 512 blocks: bx<256 sorts row bx into rowsorted; bx>=256 sorts col (bx-256) into colsorted.
// Also initializes rvec/cvec to identity.
__global__ void sort_both(const int* __restrict__ labels, int* __restrict__ rowsorted,
                          int* __restrict__ colsorted, int* __restrict__ rvec,
                          int* __restrict__ cvec) {
    __shared__ int s[NN];
    int bx = blockIdx.x;
    int i = bx & 255, mode = bx >> 8, t = threadIdx.x;
    int* rep = mode ? cvec : rvec;
    int* dst = mode ? colsorted : rowsorted;
    if (t == 0) rep[i] = i;
    s[t] = mode ? labels[t * NN + i] : labels[i * NN + t];
    __syncthreads();
    bitonic256(s, t);
    dst[i * NN + t] = s[t];
}

// rep[i] = min j with sorted row j == sorted row i. One wave per (i,j), z selects row/col.
__global__ void rep_pairs_both(const int* __restrict__ rowsorted,
                               const int* __restrict__ colsorted, int* __restrict__ rvec,
                               int* __restrict__ cvec) {
    int i = blockIdx.x;
    int wid = threadIdx.x >> 6;
    int lane = threadIdx.x & 63;
    int j = (blockIdx.y << 2) + wid;
    if (j >= i) return;
    const int* sorted = blockIdx.z ? colsorted : rowsorted;
    int* rep = blockIdx.z ? cvec : rvec;
    const int* ri = sorted + i * NN;
    const int* rj = sorted + j * NN;
    bool eq = true;
#pragma unroll
    for (int k = 0; k < NN; k += 64) eq = eq && (ri[lane + k] == rj[lane + k]);
    if (__all(eq)) {
        if (lane == 0) atomicMin(&rep[i], j);
    }
}

// ---------------- per-layer: exact relabel via hash table ----------------

__global__ void relabel_insert(const int* __restrict__ labels, const int* __restrict__ r,
                               const int* __restrict__ c, unsigned long long* __restrict__ tk,
                               unsigned* __restrict__ mp, unsigned* __restrict__ cnt,
                               unsigned* __restrict__ slotidx) {
    int m = blockIdx.x * blockDim.x + threadIdx.x;
    int i = m >> 8, j = m & 255;
    unsigned key = (unsigned)labels[m] | ((unsigned)r[i] << 16) | ((unsigned)c[j] << 24);
    unsigned long long kk = (unsigned long long)key + 1ull;  // 0 = empty
    unsigned h = ((key * 2654435761u) >> 15) & TBL_MASK;
    for (;;) {
        unsigned long long prev = atomicCAS(&tk[h], 0ull, kk);
        if (prev == 0ull || prev == kk) break;
        h = (h + 1) & TBL_MASK;
    }
    slotidx[m] = h;
    atomicMax(&mp[h], ~(unsigned)m);  // encoded min-pos, zero-init
    atomicAdd(&cnt[h], 1u);
}

__global__ void mark_slots(const unsigned long long* __restrict__ tk,
                           const unsigned* __restrict__ mp, unsigned* __restrict__ flags) {
    int s = blockIdx.x * blockDim.x + threadIdx.x;
    if (tk[s]) flags[~mp[s]] = 1u;
}

// exclusive prefix sum over 65536 unsigned; 1024 threads; 16 coalesced uint4 tiles
__global__ void scan64k(const unsigned* __restrict__ in, unsigned* __restrict__ out) {
    __shared__ unsigned wsums[16];
    __shared__ unsigned carry_s;
    int t = threadIdx.x;
    int lane = t & 63, wid = t >> 6;
    if (t == 0) carry_s = 0;
    __syncthreads();
    for (int tile = 0; tile < 16; ++tile) {
        uint4 v = ((const uint4*)in)[tile * 1024 + t];
        unsigned s0 = v.x, s1 = s0 + v.y, s2 = s1 + v.z, q = s2 + v.w;
        unsigned inc = q;
#pragma unroll
        for (int off = 1; off < 64; off <<= 1) {
            unsigned n = __shfl_up(inc, off, 64);
            if (lane >= off) inc += n;
        }
        if (lane == 63) wsums[wid] = inc;
        __syncthreads();
        if (t < 16) {
            unsigned w = wsums[t];
            unsigned wi = w;
#pragma unroll
            for (int off = 1; off < 16; off <<= 1) {
                unsigned n = __shfl_up(wi, off, 64);
                if (lane >= off) wi += n;
            }
            wsums[t] = wi - w;  // exclusive wave offset
        }
        __syncthreads();
        unsigned base = carry_s + wsums[wid] + (inc - q);
        uint4 o;
        o.x = base;
        o.y = base + s0;
        o.z = base + s1;
        o.w = base + s2;
        ((uint4*)out)[tile * 1024 + t] = o;
        __syncthreads();
        if (t == 1023) carry_s += wsums[15] + inc;  // += tile total
        __syncthreads();
    }
}

// fused: per-slot histogram write + per-pair label write (both read rankat)
__global__ void finish_layer(const unsigned long long* __restrict__ tk,
                             const unsigned* __restrict__ mp, const unsigned* __restrict__ cnt,
                             const unsigned* __restrict__ rankat,
                             const unsigned* __restrict__ slotidx, int* __restrict__ hist,
                             int* __restrict__ labels2) {
    int s = blockIdx.x * blockDim.x + threadIdx.x;
    if (s < MM) labels2[s] = (int)rankat[~mp[slotidx[s]]];
    if (tk[s]) hist[rankat[~mp[s]]] = (int)cnt[s];
}

extern "C" void kernel_launch(void* const* d_in, const int* in_sizes, int n_in,
                              void* d_out, int out_size, void* d_ws, size_t ws_size,
                              hipStream_t stream) {
    const int* x = (const int*)d_in[0];
    const int* ei = (const int*)d_in[1];
    const int E = in_sizes[1] / 2;
    int* out = (int*)d_out;  // int32 histograms

    // ---- workspace carve-up (512B aligned) ----
    char* w = (char*)d_ws;
    size_t off = 0;
    auto alloc = [&](size_t bytes) -> void* {
        void* p = w + off;
        off = (off + bytes + 511) & ~(size_t)511;
        return p;
    };
    // ---- zero region (single memset covers [0, zero_end)) ----
    unsigned long long* tkL[2] = {(unsigned long long*)alloc(TBL * 8),
                                  (unsigned long long*)alloc(TBL * 8)};
    unsigned* mpL[2] = {(unsigned*)alloc(TBL * 4), (unsigned*)alloc(TBL * 4)};
    unsigned* cntL[2] = {(unsigned*)alloc(TBL * 4), (unsigned*)alloc(TBL * 4)};
    unsigned* flagsL[2] = {(unsigned*)alloc(MM * 4), (unsigned*)alloc(MM * 4)};
    int* A = (int*)alloc(MM * 4);
    unsigned* mp0 = (unsigned*)alloc(512 * 4);
    unsigned* c0 = (unsigned*)alloc(512 * 4);
    size_t zero_end = off;
    // ---- non-zeroed scratch (fully written before read, every launch) ----
    unsigned* slotidx = (unsigned*)alloc(MM * 4);
    unsigned* rankat = (unsigned*)alloc(MM * 4);
    int* labels = (int*)alloc(MM * 4);
    int* labels2 = (int*)alloc(MM * 4);
    int* rowsorted = (int*)alloc(MM * 4);
    int* colsorted = (int*)alloc(MM * 4);
    int* rvec = (int*)alloc(NN * 4);
    int* cvec = (int*)alloc(NN * 4);
    unsigned* rank0 = (unsigned*)alloc(512 * 4);

    (void)hipMemsetAsync(d_ws, 0, zero_end, stream);
    (void)hipMemsetAsync(d_out, 0, (size_t)out_size * sizeof(int), stream);

    // ---- adjacency + initial coloring ----
    build_adj<<<(E + 255) / 256, 256, 0, stream>>>(ei, A, E);
    init_key_pass<<<MM / 256, 256, 0, stream>>>(x, A, mp0, c0);
    rank0_fused<<<1, 512, 0, stream>>>(mp0, c0, rank0, out);
    write_labels0<<<MM / 256, 256, 0, stream>>>(x, A, rank0, labels);

    // ---- refinement layers ----
    int* lab = labels;
    int* lab2 = labels2;
    for (int layer = 0; layer < 2; ++layer) {
        sort_both<<<2 * NN, NN, 0, stream>>>(lab, rowsorted, colsorted, rvec, cvec);
        rep_pairs_both<<<dim3(NN, NN / 4, 2), 256, 0, stream>>>(rowsorted, colsorted, rvec, cvec);
        relabel_insert<<<MM / 256, 256, 0, stream>>>(lab, rvec, cvec, tkL[layer], mpL[layer],
                                                     cntL[layer], slotidx);
        mark_slots<<<TBL / 256, 256, 0, stream>>>(tkL[layer], mpL[layer], flagsL[layer]);
        scan64k<<<1, 1024, 0, stream>>>(flagsL[layer], rankat);
        finish_layer<<<TBL / 256, 256, 0, stream>>>(tkL[layer], mpL[layer], cntL[layer], rankat,
                                                    slotidx, out + (size_t)(layer + 1) * MM, lab2);
        int* tmp = lab;
        lab = lab2;
        lab2 = tmp;
    }
}